// Round 17
// baseline (48.142 us; speedup 1.0000x reference)
//
#include <hip/hip_runtime.h>
#include <stdint.h>

#define N_SAMP 8192
#define D_DIM  512
#define P_DIM  1024
#define DT     0.1875f

typedef float f32x4 __attribute__((ext_vector_type(4)));
typedef float f32x2 __attribute__((ext_vector_type(2)));
typedef short bf16x8 __attribute__((ext_vector_type(8)));
typedef unsigned short u16;

__device__ __forceinline__ u16 f2bf(float x){
    unsigned int u = __float_as_uint(x);
    return (u16)((u + 0x7FFFu + ((u >> 16) & 1u)) >> 16);
}

__device__ __forceinline__ void load_lds16(const void* g, void* l){
    __builtin_amdgcn_global_load_lds(
        (const __attribute__((address_space(1))) void*)(uintptr_t)g,
        (__attribute__((address_space(3))) void*)(uint32_t)(uintptr_t)l,
        16, 0, 0);
}

// ---- prep: 4 independent block ranges (R11-proven, unchanged) ----
__global__ __launch_bounds__(256) void k_prep(const float4* __restrict__ z4,
                                              u16* __restrict__ zb,
                                              const float* __restrict__ A,
                                              float* __restrict__ inv,
                                              u16* __restrict__ AnT,
                                              float* __restrict__ gpart,
                                              float* __restrict__ out){
    const int tid = threadIdx.x;
    const int b = blockIdx.x;
    if (b < 4096){
        int i = b * 256 + tid;                    // N*D/4 float4s
        if (i == 0) out[0] = 0.f;                 // stream-ordered before reduce
        float4 v = z4[i];
        ushort4 o;
        o.x = f2bf(v.x); o.y = f2bf(v.y); o.z = f2bf(v.z); o.w = f2bf(v.w);
        ((ushort4*)zb)[i] = o;
        return;
    }
    if (b < 4128){                                // norms: 32 p-columns/block
        __shared__ float red[8][32];
        const int p0 = (b - 4096) * 32;
        const int pl = tid & 31, dg = tid >> 5;
        float s = 0.f;
        #pragma unroll 8
        for (int i = 0; i < 64; ++i){
            float v = A[(size_t)(dg + 8 * i) * P_DIM + p0 + pl];
            s += v * v;
        }
        red[dg][pl] = s;
        __syncthreads();
        if (tid < 32){
            float t = 0.f;
            #pragma unroll
            for (int g = 0; g < 8; ++g) t += red[g][tid];
            inv[p0 + tid] = 1.0f / fmaxf(sqrtf(t), 1e-8f);
        }
        return;
    }
    if (b < 4640){                                // pure transpose tile 32x32
        __shared__ float tile[32][33];
        const int t = b - 4128;
        const int p0 = (t & 31) * 32, d0 = (t >> 5) * 32;
        const int tx = tid & 31, ty = tid >> 5;   // 32 x 8
        #pragma unroll
        for (int j = 0; j < 4; ++j)
            tile[ty + j * 8][tx] = A[(size_t)(d0 + ty + j * 8) * P_DIM + p0 + tx];
        __syncthreads();
        #pragma unroll
        for (int j = 0; j < 4; ++j){
            int pp = ty + j * 8;
            AnT[(size_t)(p0 + pp) * D_DIM + d0 + tx] = f2bf(tile[tx][pp]);
        }
        return;
    }
    int i = (b - 4640) * 256 + tid;               // zero gpart
    ((float4*)gpart)[i] = (float4){0.f, 0.f, 0.f, 0.f};
}

// One K-step: MFMAs consume B regs BC (loaded last iter); prefetch BN (B for
// KT+1, from L2-resident AnT) + next A tile. The barrier's vmcnt(0) drain is
// the completion point for loads issued LAST iteration (R5-proven pattern).
#define GEMM_ITER(KT, BC, BN)                                                  \
  {                                                                            \
    __syncthreads();                                                           \
    if ((KT) < 7){                                                             \
      _Pragma("unroll")                                                        \
      for (int ks = 0; ks < 2; ++ks)                                           \
        _Pragma("unroll")                                                      \
        for (int j = 0; j < 2; ++j)                                            \
          BN[ks][j] = *(const bf16x8*)&gB[(size_t)j * 16 * D_DIM +             \
                                          ((KT) + 1) * 64 + ks * 32];          \
      char* la = lbase + (((KT) + 1) & 1) * 16384;                             \
      _Pragma("unroll")                                                        \
      for (int h = 0; h < 2; ++h)                                              \
        load_lds16(gA + (size_t)h * 64 * D_DIM + ((KT) + 1) * 64,              \
                   la + h * 8192);                                             \
    }                                                                          \
    const u16* Ab = (const u16*)smem4 + ((KT) & 1) * 8192;                     \
    _Pragma("unroll")                                                          \
    for (int ks = 0; ks < 2; ++ks){                                            \
      bf16x8 af[4];                                                            \
      _Pragma("unroll")                                                        \
      for (int i = 0; i < 4; ++i)                                              \
        af[i] = *(const bf16x8*)&Ab[(wm + i * 16 + r) * 64 +                   \
                                    (((ks * 4 + kg) ^ (r & 7)) << 3)];         \
      _Pragma("unroll")                                                        \
      for (int i = 0; i < 4; ++i)                                              \
        _Pragma("unroll")                                                      \
        for (int j = 0; j < 2; ++j)                                            \
          acc[i][j] = __builtin_amdgcn_mfma_f32_16x16x32_bf16(                 \
              af[i], BC[ks][j], acc[i][j], 0, 0, 0);                           \
    }                                                                          \
  }

// ---- fused GEMM + ECF: 128x128 tile, 8 waves, A LDS-dbuf 32K, B reg-dbuf ----
__global__ __launch_bounds__(512) void k_gemm_ecf(const u16* __restrict__ zb,
                                                  const u16* __restrict__ AnT,
                                                  const float* __restrict__ inv,
                                                  float* __restrict__ gpart){
    __shared__ uint4 smem4[2048];                 // 32 KiB: 2 x 16 KiB A bufs
    const int tid = threadIdx.x;
    // XCD swizzle (512 blocks, 8 XCDs round-robin): each XCD owns 8 bm-groups
    const int swz = (blockIdx.x & 7) * 64 + (blockIdx.x >> 3);
    const int bm = swz >> 3, bn = swz & 7;
    const int m0 = bm << 7, n0 = bn << 7;
    const int w = tid >> 6, lane = tid & 63;      // 8 waves
    const int r = lane & 15, kg = lane >> 4;
    const int wm = (w >> 2) << 6;                 // row half
    const int wn = (w & 3) << 5;                  // col quarter

    // A staging: thread t (0..511) -> LDS granule (row=t>>3, g=t&7); source
    // global granule (t&7)^(row&7) (inverse of the read swizzle).
    const int srow = tid >> 3;                    // 0..63
    const int gsw  = ((tid & 7) ^ (srow & 7)) << 3;
    const u16* gA = zb + (size_t)(m0 + srow) * D_DIM + gsw;
    char* lbase = (char*)smem4 + w * 1024;        // wave-uniform base

    // B fragments: lane-fixed global row base (AnT is 1 MB, L2-resident)
    const u16* gB = AnT + (size_t)(n0 + wn + r) * D_DIM + kg * 8;

    f32x4 acc[4][2] = {};
    bf16x8 bA[2][2], bB[2][2];                    // register double-buffer for B

    // prologue: A tile 0 -> buf0, B tile 0 -> bA
    #pragma unroll
    for (int h = 0; h < 2; ++h)
        load_lds16(gA + (size_t)h * 64 * D_DIM, lbase + h * 8192);
    #pragma unroll
    for (int ks = 0; ks < 2; ++ks)
        #pragma unroll
        for (int j = 0; j < 2; ++j)
            bA[ks][j] = *(const bf16x8*)&gB[(size_t)j * 16 * D_DIM + ks * 32];

    for (int kt2 = 0; kt2 < 4; ++kt2){            // unroll-by-2: static reg roles
        GEMM_ITER(2 * kt2,     bA, bB);
        GEMM_ITER(2 * kt2 + 1, bB, bA);
    }

    // ---- epilogue: packed (cos,sin) Chebyshev recurrence, reduce rows ----
    __syncthreads();                              // all waves done with A bufs
    float* epil = (float*)smem4;                  // [8 waves][32 j][32 cols] 32K
    #pragma unroll
    for (int jn = 0; jn < 2; ++jn){
        const float sc = inv[n0 + wn + jn * 16 + r] * DT;   // per-column scale
        f32x2 sum[16];
        #pragma unroll
        for (int k = 0; k < 16; ++k) sum[k] = (f32x2){0.f, 0.f};
        #pragma unroll
        for (int i = 0; i < 4; ++i){
            #pragma unroll
            for (int q = 0; q < 4; ++q){
                float x = acc[i][jn][q] * sc;     // theta = proj_norm * t1
                float s1, c1;
                __sincosf(x, &s1, &c1);
                float tc = c1 + c1;
                f32x2 prev = {1.f, 0.f};
                f32x2 curv = {c1, s1};
                sum[0] += curv;
                #pragma unroll
                for (int k = 2; k <= 16; ++k){
                    f32x2 nxt = tc * curv - prev; // v_pk_fma_f32
                    sum[k - 1] += nxt;
                    prev = curv; curv = nxt;
                }
            }
        }
        // lanes l, l^16, l^32, l^48 share a column -> sum the 4 row-groups
        #pragma unroll
        for (int k = 0; k < 16; ++k){
            f32x2 o;
            o.x = __shfl_xor(sum[k].x, 16); o.y = __shfl_xor(sum[k].y, 16);
            sum[k] += o;
            o.x = __shfl_xor(sum[k].x, 32); o.y = __shfl_xor(sum[k].y, 32);
            sum[k] += o;
        }
        if (lane < 16){
            const int cl = jn * 16 + lane;        // 0..31 within wave's cols
            #pragma unroll
            for (int k = 0; k < 16; ++k){
                epil[(w * 32 + k)      * 32 + cl] = sum[k].x;
                epil[(w * 32 + 16 + k) * 32 + cl] = sum[k].y;
            }
        }
    }
    __syncthreads();
    // fold row-halves (waves w and w+4 share cols), atomic into gpart
    for (int f0 = 0; f0 < 4096; f0 += 512){
        int f = f0 + tid;
        int cl = f & 127, j = f >> 7;             // p-in-tile, j-index
        int whi = cl >> 5, cll = cl & 31;         // col quarter, col-in-quarter
        float v = epil[((whi    ) * 32 + j) * 32 + cll] +
                  epil[((whi + 4) * 32 + j) * 32 + cll];
        atomicAdd(&gpart[j * P_DIM + n0 + cl], v);
    }
}

// ---- final: weighted reduce of gpart[32][1024] -> scalar ----
__global__ __launch_bounds__(256) void k_reduce(const float* __restrict__ gpart,
                                                float* __restrict__ out){
    const int tid = threadIdx.x;
    const int idx = blockIdx.x * 256 + tid;       // 0..32767 linear
    const int j = idx >> 10;                      // 0..15 cos(k=j+1), 16..31 sin
    float s = gpart[idx];
    const int k = (j & 15) + 1;
    float tk = (float)k * DT;
    float phik = expf(-0.5f * tk * tk);
    float wk = ((k == 16) ? DT : 2.f * DT) * phik;
    float mean = s * (1.f / (float)N_SAMP);
    float diff = (j < 16) ? (mean - phik) : mean;
    float term = diff * diff * wk;
    #pragma unroll
    for (int o = 32; o > 0; o >>= 1) term += __shfl_xor(term, o);
    __shared__ float red[4];
    if ((tid & 63) == 0) red[tid >> 6] = term;
    __syncthreads();
    if (tid == 0)
        atomicAdd(out, (red[0] + red[1] + red[2] + red[3]) *
                       ((float)N_SAMP / (float)P_DIM));
}

extern "C" void kernel_launch(void* const* d_in, const int* in_sizes, int n_in,
                              void* d_out, int out_size, void* d_ws, size_t ws_size,
                              hipStream_t stream){
    const float* z = (const float*)d_in[0];
    const float* A = (const float*)d_in[1];
    char* ws = (char*)d_ws;
    float* inv   = (float*)(ws);                  // 4 KiB
    float* gpart = (float*)(ws + 8192);           // 128 KiB [32][1024] f32
    u16*   AnT   = (u16*)  (ws + 139264);         // 1 MiB  [1024][512] bf16
    u16*   zb    = (u16*)  (ws + 1187840);        // 8 MiB  [8192][512] bf16
    float* out   = (float*)d_out;

    hipLaunchKernelGGL(k_prep,     dim3(4672), dim3(256), 0, stream,
                       (const float4*)z, zb, A, inv, AnT, gpart, out);
    hipLaunchKernelGGL(k_gemm_ecf, dim3(512),  dim3(512), 0, stream,
                       zb, AnT, inv, gpart);
    hipLaunchKernelGGL(k_reduce,   dim3(128),  dim3(256), 0, stream, gpart, out);
}

// Round 18
// 41.382 us; speedup vs baseline: 1.1634x; 1.1634x over previous
//
#include <hip/hip_runtime.h>
#include <stdint.h>

#define N_SAMP 8192
#define D_DIM  512
#define P_DIM  1024
#define DT     0.1875f

typedef float f32x4 __attribute__((ext_vector_type(4)));
typedef float f32x2 __attribute__((ext_vector_type(2)));
typedef short bf16x8 __attribute__((ext_vector_type(8)));
typedef unsigned short u16;

__device__ __forceinline__ u16 f2bf(float x){
    unsigned int u = __float_as_uint(x);
    return (u16)((u + 0x7FFFu + ((u >> 16) & 1u)) >> 16);
}

__device__ __forceinline__ void load_lds16(const void* g, void* l){
    __builtin_amdgcn_global_load_lds(
        (const __attribute__((address_space(1))) void*)(uintptr_t)g,
        (__attribute__((address_space(3))) void*)(uint32_t)(uintptr_t)l,
        16, 0, 0);
}

// ---- prep: 4 independent block ranges (R11-proven) ----
//  [0,4096)    : z fp32 -> bf16 (vectorized, high-TLP streaming)
//  [4096,4128) : column inverse norms of A
//  [4128,4640) : pure transpose A -> AnT bf16
//  [4640,4672) : zero gpart accumulator (32x1024 f32)
__global__ __launch_bounds__(256) void k_prep(const float4* __restrict__ z4,
                                              u16* __restrict__ zb,
                                              const float* __restrict__ A,
                                              float* __restrict__ inv,
                                              u16* __restrict__ AnT,
                                              float* __restrict__ gpart,
                                              float* __restrict__ out){
    const int tid = threadIdx.x;
    const int b = blockIdx.x;
    if (b < 4096){
        int i = b * 256 + tid;                    // N*D/4 float4s
        if (i == 0) out[0] = 0.f;                 // stream-ordered before reduce
        float4 v = z4[i];
        ushort4 o;
        o.x = f2bf(v.x); o.y = f2bf(v.y); o.z = f2bf(v.z); o.w = f2bf(v.w);
        ((ushort4*)zb)[i] = o;
        return;
    }
    if (b < 4128){                                // norms: 32 p-columns/block
        __shared__ float red[8][32];
        const int p0 = (b - 4096) * 32;
        const int pl = tid & 31, dg = tid >> 5;
        float s = 0.f;
        #pragma unroll 8
        for (int i = 0; i < 64; ++i){
            float v = A[(size_t)(dg + 8 * i) * P_DIM + p0 + pl];
            s += v * v;
        }
        red[dg][pl] = s;
        __syncthreads();
        if (tid < 32){
            float t = 0.f;
            #pragma unroll
            for (int g = 0; g < 8; ++g) t += red[g][tid];
            inv[p0 + tid] = 1.0f / fmaxf(sqrtf(t), 1e-8f);
        }
        return;
    }
    if (b < 4640){                                // pure transpose tile 32x32
        __shared__ float tile[32][33];
        const int t = b - 4128;
        const int p0 = (t & 31) * 32, d0 = (t >> 5) * 32;
        const int tx = tid & 31, ty = tid >> 5;   // 32 x 8
        #pragma unroll
        for (int j = 0; j < 4; ++j)
            tile[ty + j * 8][tx] = A[(size_t)(d0 + ty + j * 8) * P_DIM + p0 + tx];
        __syncthreads();
        #pragma unroll
        for (int j = 0; j < 4; ++j){
            int pp = ty + j * 8;
            AnT[(size_t)(p0 + pp) * D_DIM + d0 + tx] = f2bf(tile[tx][pp]);
        }
        return;
    }
    int i = (b - 4640) * 256 + tid;               // zero gpart
    ((float4*)gpart)[i] = (float4){0.f, 0.f, 0.f, 0.f};
}

// ---- fused GEMM + ECF: 128x128 tile, 8 waves (2x4), 16 waves/CU ----
// A,B via global_load_lds (pre-swizzled source, linear LDS dest), XOR-swizzled
// ds_read, double-buffered. Proven optimum (R11/R15: 41.4-41.6 us total).
__global__ __launch_bounds__(512) void k_gemm_ecf(const u16* __restrict__ zb,
                                                  const u16* __restrict__ AnT,
                                                  const float* __restrict__ inv,
                                                  float* __restrict__ gpart){
    __shared__ uint4 smem4[4096];                 // 64 KiB: 2 x (A 16K + B 16K)
    const int tid = threadIdx.x;
    // XCD swizzle (512 blocks, 8 XCDs round-robin): each XCD owns 8 bm-groups
    const int swz = (blockIdx.x & 7) * 64 + (blockIdx.x >> 3);
    const int bm = swz >> 3, bn = swz & 7;
    const int m0 = bm << 7, n0 = bn << 7;
    const int w = tid >> 6, lane = tid & 63;      // 8 waves
    const int r = lane & 15, kg = lane >> 4;
    const int wm = (w >> 2) << 6;                 // row half
    const int wn = (w & 3) << 5;                  // col quarter

    // staging: thread t (0..511) -> LDS granule (row=t>>3, g=t&7); source
    // global granule (t&7)^(row&7) (inverse of the read swizzle).
    const int srow = tid >> 3;                    // 0..63
    const int gsw  = ((tid & 7) ^ (srow & 7)) << 3;
    const u16* gA = zb  + (size_t)(m0 + srow) * D_DIM + gsw;
    const u16* gB = AnT + (size_t)(n0 + srow) * D_DIM + gsw;
    char* lbase = (char*)smem4 + w * 1024;        // wave-uniform base

    f32x4 acc[4][2] = {};

    // prologue: stage tile 0 into buf0 (A halves, B halves)
    #pragma unroll
    for (int h = 0; h < 2; ++h){
        load_lds16(gA + (size_t)h * 64 * D_DIM, lbase + h * 8192);
        load_lds16(gB + (size_t)h * 64 * D_DIM, lbase + 16384 + h * 8192);
    }

    for (int kt = 0; kt < 8; ++kt){
        const int cur = kt & 1;
        __syncthreads();                          // cur tile ready, prev reads done
        if (kt < 7){                              // issue next tile under MFMAs
            char* la = lbase + ((kt + 1) & 1) * 32768;
            #pragma unroll
            for (int h = 0; h < 2; ++h){
                load_lds16(gA + (size_t)h * 64 * D_DIM + (kt + 1) * 64, la + h * 8192);
                load_lds16(gB + (size_t)h * 64 * D_DIM + (kt + 1) * 64, la + 16384 + h * 8192);
            }
        }
        const u16* Ab = (const u16*)smem4 + cur * 16384;
        const u16* Bb = Ab + 8192;
        #pragma unroll
        for (int ks = 0; ks < 2; ++ks){
            bf16x8 af[4], bfr[2];
            #pragma unroll
            for (int i = 0; i < 4; ++i)
                af[i] = *(const bf16x8*)&Ab[(wm + i * 16 + r) * 64 +
                                            (((ks * 4 + kg) ^ (r & 7)) << 3)];
            #pragma unroll
            for (int j = 0; j < 2; ++j)
                bfr[j] = *(const bf16x8*)&Bb[(wn + j * 16 + r) * 64 +
                                             (((ks * 4 + kg) ^ (r & 7)) << 3)];
            #pragma unroll
            for (int i = 0; i < 4; ++i)
                #pragma unroll
                for (int j = 0; j < 2; ++j)
                    acc[i][j] = __builtin_amdgcn_mfma_f32_16x16x32_bf16(
                        af[i], bfr[j], acc[i][j], 0, 0, 0);
        }
    }

    // ---- epilogue: packed (cos,sin) Chebyshev recurrence, reduce rows ----
    __syncthreads();                              // all waves done with tiles
    float* epil = (float*)smem4;                  // [8 waves][32 j][32 cols]
    #pragma unroll
    for (int jn = 0; jn < 2; ++jn){
        const float sc = inv[n0 + wn + jn * 16 + r] * DT;   // per-column scale
        f32x2 sum[16];
        #pragma unroll
        for (int k = 0; k < 16; ++k) sum[k] = (f32x2){0.f, 0.f};
        #pragma unroll
        for (int i = 0; i < 4; ++i){
            #pragma unroll
            for (int q = 0; q < 4; ++q){
                float x = acc[i][jn][q] * sc;     // theta = proj_norm * t1
                float s1, c1;
                __sincosf(x, &s1, &c1);           // shared range reduction
                float tc = c1 + c1;
                f32x2 prev = {1.f, 0.f};
                f32x2 curv = {c1, s1};
                sum[0] += curv;
                #pragma unroll
                for (int k = 2; k <= 16; ++k){
                    f32x2 nxt = tc * curv - prev; // v_pk_fma_f32
                    sum[k - 1] += nxt;
                    prev = curv; curv = nxt;
                }
            }
        }
        // lanes l, l^16, l^32, l^48 share a column -> sum the 4 row-groups
        #pragma unroll
        for (int k = 0; k < 16; ++k){
            f32x2 o;
            o.x = __shfl_xor(sum[k].x, 16); o.y = __shfl_xor(sum[k].y, 16);
            sum[k] += o;
            o.x = __shfl_xor(sum[k].x, 32); o.y = __shfl_xor(sum[k].y, 32);
            sum[k] += o;
        }
        if (lane < 16){
            const int cl = jn * 16 + lane;        // 0..31 within wave's cols
            #pragma unroll
            for (int k = 0; k < 16; ++k){
                epil[(w * 32 + k)      * 32 + cl] = sum[k].x;
                epil[(w * 32 + 16 + k) * 32 + cl] = sum[k].y;
            }
        }
    }
    __syncthreads();
    // fold row-halves (waves w and w+4 share cols), atomic into gpart
    for (int f0 = 0; f0 < 4096; f0 += 512){
        int f = f0 + tid;
        int cl = f & 127, j = f >> 7;             // p-in-tile, j-index
        int whi = cl >> 5, cll = cl & 31;         // col quarter, col-in-quarter
        float v = epil[((whi    ) * 32 + j) * 32 + cll] +
                  epil[((whi + 4) * 32 + j) * 32 + cll];
        atomicAdd(&gpart[j * P_DIM + n0 + cl], v);
    }
}

// ---- final: weighted reduce of gpart[32][1024] -> scalar ----
__global__ __launch_bounds__(256) void k_reduce(const float* __restrict__ gpart,
                                                float* __restrict__ out){
    const int tid = threadIdx.x;
    const int idx = blockIdx.x * 256 + tid;       // 0..32767 linear
    const int j = idx >> 10;                      // 0..15 cos(k=j+1), 16..31 sin
    float s = gpart[idx];
    const int k = (j & 15) + 1;
    float tk = (float)k * DT;
    float phik = expf(-0.5f * tk * tk);
    float wk = ((k == 16) ? DT : 2.f * DT) * phik;
    float mean = s * (1.f / (float)N_SAMP);
    float diff = (j < 16) ? (mean - phik) : mean;
    float term = diff * diff * wk;
    #pragma unroll
    for (int o = 32; o > 0; o >>= 1) term += __shfl_xor(term, o);
    __shared__ float red[4];
    if ((tid & 63) == 0) red[tid >> 6] = term;
    __syncthreads();
    if (tid == 0)
        atomicAdd(out, (red[0] + red[1] + red[2] + red[3]) *
                       ((float)N_SAMP / (float)P_DIM));
}

extern "C" void kernel_launch(void* const* d_in, const int* in_sizes, int n_in,
                              void* d_out, int out_size, void* d_ws, size_t ws_size,
                              hipStream_t stream){
    const float* z = (const float*)d_in[0];
    const float* A = (const float*)d_in[1];
    char* ws = (char*)d_ws;
    float* inv   = (float*)(ws);                  // 4 KiB
    float* gpart = (float*)(ws + 8192);           // 128 KiB [32][1024] f32
    u16*   AnT   = (u16*)  (ws + 139264);         // 1 MiB  [1024][512] bf16
    u16*   zb    = (u16*)  (ws + 1187840);        // 8 MiB  [8192][512] bf16
    float* out   = (float*)d_out;

    hipLaunchKernelGGL(k_prep,     dim3(4672), dim3(256), 0, stream,
                       (const float4*)z, zb, A, inv, AnT, gpart, out);
    hipLaunchKernelGGL(k_gemm_ecf, dim3(512),  dim3(512), 0, stream,
                       zb, AnT, inv, gpart);
    hipLaunchKernelGGL(k_reduce,   dim3(128),  dim3(256), 0, stream, gpart, out);
}